// Round 1
// baseline (758.383 us; speedup 1.0000x reference)
//
#include <hip/hip_runtime.h>

// Fused windowed masked attention, one workgroup per (b,p,h) slice.
// B=2,P=64,H=8 -> 1024 slices; I=J=256, D=64. fp32 in/out, bf16 MFMA inside.
//
// Layout notes (gfx950 mfma_f32_16x16x32_bf16, all HW-verified mappings):
//   A-frag: A[m=lane&15][k=(lane>>4)*8+jj], jj=0..7
//   B-frag: B[k=(lane>>4)*8+jj][n=lane&15]
//   C/D   : col=lane&15, row=(lane>>4)*4+reg
// We compute simT = K*Q^T (rows=j, cols=i) so softmax-over-j reduces in-lane
// (4 regs x 16 tiles) plus shfl_xor(16),shfl_xor(32).

typedef short short8 __attribute__((ext_vector_type(8)));
typedef float f32x4 __attribute__((ext_vector_type(4)));
typedef int int4v __attribute__((ext_vector_type(4)));

__device__ __forceinline__ unsigned bf16r(float x) {
  unsigned u = __float_as_uint(x);
  return (u + 0x7FFFu + ((u >> 16) & 1u)) >> 16;  // round-to-nearest-even
}
__device__ __forceinline__ unsigned pk(float a, float b) {
  return bf16r(a) | (bf16r(b) << 16);
}
__device__ __forceinline__ short8 pack8(float4 a, float4 b) {
  int4v t;
  t[0] = (int)pk(a.x, a.y); t[1] = (int)pk(a.z, a.w);
  t[2] = (int)pk(b.x, b.y); t[3] = (int)pk(b.z, b.w);
  return __builtin_bit_cast(short8, t);
}

__global__ __launch_bounds__(256, 2)
void WindowedMaskedAttentionCalculation_72189810311255_kernel(
    const float* __restrict__ q, const float* __restrict__ k,
    const float* __restrict__ v, const float* __restrict__ pos,
    const float* __restrict__ msk, float* __restrict__ out) {
  // K bf16 row-major [256][64], 128B rows; 16B granule swizzled by (j&7).
  // Vt bf16 [64][256] (V transposed), 512B rows; granule swizzled by (d&15).
  __shared__ unsigned short Kb[16384];   // 32 KiB
  __shared__ unsigned short Vt[16384];   // 32 KiB  -> 64 KiB total, 2 WG/CU

  const int s = blockIdx.x;
  const int tid = threadIdx.x;
  const size_t qkvOff = (size_t)s * 16384;   // 256*64
  const size_t pmOff = (size_t)s * 65536;    // 256*256

  // ---------------- stage K (swizzled) and V^T (swizzled) ----------------
  const float4* K4 = (const float4*)(k + qkvOff);
  const float4* V4 = (const float4*)(v + qkvOff);
#pragma unroll
  for (int it = 0; it < 16; ++it) {
    int f4 = it * 256 + tid;        // 0..4095, coalesced float4 stream
    int j = f4 >> 4;                // row 0..255
    int c4 = f4 & 15;               // float4 index within row (d = 4*c4)
    float4 kv = K4[f4];
    unsigned lo = pk(kv.x, kv.y), hi = pk(kv.z, kv.w);
    int gs = (c4 >> 1) ^ (j & 7);   // 16B-granule swizzle
    *(uint2*)&Kb[j * 64 + gs * 8 + (c4 & 1) * 4] = make_uint2(lo, hi);

    float4 vv = V4[f4];
    float vals[4] = {vv.x, vv.y, vv.z, vv.w};
    int dc = c4 * 4;
#pragma unroll
    for (int c = 0; c < 4; ++c) {   // transpose store (one-time; minor conflicts)
      int d = dc + c;
      int gv = (j >> 3) ^ (d & 15);
      Vt[d * 256 + gv * 8 + (j & 7)] = (unsigned short)bf16r(vals[c]);
    }
  }
  __syncthreads();

  // ---------------- per-wave attention over 16-row i-chunks ----------------
  const int w = tid >> 6, l = tid & 63, g = l >> 4, il = l & 15;
  const float* Qs = q + qkvOff;
  const float4* Pos4 = (const float4*)(pos + pmOff);
  const float4* Msk4 = (const float4*)(msk + pmOff);
  float* Out = out + qkvOff;
  const f32x4 zero = {0.f, 0.f, 0.f, 0.f};

#pragma unroll 1
  for (int chunk = 0; chunk < 4; ++chunk) {
    const int i0 = (w * 4 + chunk) * 16;
    const int irow = i0 + il;

    // Q B-frags (B[k=d][n=i] = Q[i][d]): 8 consecutive d per lane, 2 k-steps
    const float4* Qr = (const float4*)(Qs + (size_t)irow * 64);
    short8 qf0 = pack8(Qr[2 * g], Qr[2 * g + 1]);
    short8 qf1 = pack8(Qr[8 + 2 * g], Qr[9 + 2 * g]);

    // QK^T: simT[j=16jt+4g+r][i=irow], j streamed over 16 tiles in regs
    float sv[16][4];
#pragma unroll
    for (int jt = 0; jt < 16; ++jt) {
      float4 pf = Pos4[(size_t)irow * 64 + jt * 4 + g];  // pos[i][16jt+4g ..+3]
      float4 mf = Msk4[(size_t)irow * 64 + jt * 4 + g];
      int j16 = jt * 16 + il;
      const short8* kr = (const short8*)&Kb[j16 * 64];
      short8 kf0 = kr[(0 + g) ^ (j16 & 7)];   // K[j16][d=8g..8g+7]
      short8 kf1 = kr[(4 + g) ^ (j16 & 7)];   // K[j16][d=32+8g..]
      f32x4 acc = __builtin_amdgcn_mfma_f32_16x16x32_bf16(kf0, qf0, zero, 0, 0, 0);
      acc = __builtin_amdgcn_mfma_f32_16x16x32_bf16(kf1, qf1, acc, 0, 0, 0);
      sv[jt][0] = (acc[0] * 0.125f + pf.x) * mf.x;
      sv[jt][1] = (acc[1] * 0.125f + pf.y) * mf.y;
      sv[jt][2] = (acc[2] * 0.125f + pf.z) * mf.z;
      sv[jt][3] = (acc[3] * 0.125f + pf.w) * mf.w;
    }

    // ---- softmax over j (in-lane 64 values, then xor16/xor32 across g) ----
    float mx = -3.4e38f;
#pragma unroll
    for (int jt = 0; jt < 16; ++jt)
#pragma unroll
      for (int r = 0; r < 4; ++r) mx = fmaxf(mx, sv[jt][r]);
    mx = fmaxf(mx, __shfl_xor(mx, 16));
    mx = fmaxf(mx, __shfl_xor(mx, 32));
    float sum = 0.f;
#pragma unroll
    for (int jt = 0; jt < 16; ++jt)
#pragma unroll
      for (int r = 0; r < 4; ++r) {
        float e = exp2f((sv[jt][r] - mx) * 1.44269504088896340736f);
        sv[jt][r] = e;
        sum += e;
      }
    sum += __shfl_xor(sum, 16);
    sum += __shfl_xor(sum, 32);
    float rcp = 1.0f / sum;   // deferred normalization

    // pack unnormalized P to bf16 pairs: pd[tile][0]=(r0,r1), [1]=(r2,r3)
    unsigned pd[16][2];
#pragma unroll
    for (int jt = 0; jt < 16; ++jt) {
      pd[jt][0] = pk(sv[jt][0], sv[jt][1]);
      pd[jt][1] = pk(sv[jt][2], sv[jt][3]);
    }

    // ---- PV: transform P C-layout -> A-frag via ds_bpermute, MFMA with Vt ----
    f32x4 ao[4] = {zero, zero, zero, zero};
    const int addrA = (((g & 1) * 2) * 16 + il) * 4;  // source lane * 4
    const int addrB = addrA + 64;                     // +16 lanes
    const bool hi = (g >> 1) != 0;
#pragma unroll
    for (int kt = 0; kt < 8; ++kt) {
      int t0 = 2 * kt, t1 = t0 + 1;
      int a0 = __builtin_amdgcn_ds_bpermute(addrA, (int)pd[t0][0]);
      int b0 = __builtin_amdgcn_ds_bpermute(addrA, (int)pd[t1][0]);
      int a1 = __builtin_amdgcn_ds_bpermute(addrA, (int)pd[t0][1]);
      int b1 = __builtin_amdgcn_ds_bpermute(addrA, (int)pd[t1][1]);
      int a2 = __builtin_amdgcn_ds_bpermute(addrB, (int)pd[t0][0]);
      int b2 = __builtin_amdgcn_ds_bpermute(addrB, (int)pd[t1][0]);
      int a3 = __builtin_amdgcn_ds_bpermute(addrB, (int)pd[t0][1]);
      int b3 = __builtin_amdgcn_ds_bpermute(addrB, (int)pd[t1][1]);
      int4v av;
      av[0] = hi ? b0 : a0;
      av[1] = hi ? b1 : a1;
      av[2] = hi ? b2 : a2;
      av[3] = hi ? b3 : a3;
      short8 af = __builtin_bit_cast(short8, av);   // P[i=il][j=32kt+8g ..+7]
#pragma unroll
      for (int dt = 0; dt < 4; ++dt) {
        int d = dt * 16 + il;
        const short8* vr = (const short8*)&Vt[d * 256];
        short8 vf = vr[(4 * kt + g) ^ il];          // V[j=32kt+8g..][d]
        ao[dt] = __builtin_amdgcn_mfma_f32_16x16x32_bf16(af, vf, ao[dt], 0, 0, 0);
      }
    }

    // ---- epilogue: scale rows by 1/l and store (full-line coalesced) ----
    float rl[4];
#pragma unroll
    for (int r = 0; r < 4; ++r) rl[r] = __shfl(rcp, g * 4 + r);
#pragma unroll
    for (int dt = 0; dt < 4; ++dt)
#pragma unroll
      for (int r = 0; r < 4; ++r)
        Out[(size_t)(i0 + g * 4 + r) * 64 + dt * 16 + il] = ao[dt][r] * rl[r];
  }
}

extern "C" void kernel_launch(void* const* d_in, const int* in_sizes, int n_in,
                              void* d_out, int out_size, void* d_ws, size_t ws_size,
                              hipStream_t stream) {
  const float* q = (const float*)d_in[0];
  const float* k = (const float*)d_in[1];
  const float* v = (const float*)d_in[2];
  const float* pos = (const float*)d_in[3];
  const float* msk = (const float*)d_in[4];
  float* out = (float*)d_out;
  WindowedMaskedAttentionCalculation_72189810311255_kernel<<<1024, 256, 0, stream>>>(
      q, k, v, pos, msk, out);
}